// Round 1
// baseline (2888.799 us; speedup 1.0000x reference)
//
#include <hip/hip_runtime.h>
#include <cstdint>
#include <cstddef>

// ============================================================================
// Swin-style window-attention block, MI355X (gfx950).
// Pipeline: weight-prep -> LN1(gather) -> QKV GEMM -> windowed attention ->
//           out-proj GEMM -> LN2(+residual) -> MLP1+GELU -> MLP2+res -> scatter
// All GEMMs: bf16 MFMA 16x16x32, fp32 accum. Residual spine fp32 (x re-read).
// Workspace need: ~946 MB (assumed available).
// ============================================================================

typedef unsigned short u16;
typedef unsigned int u32;
typedef __attribute__((ext_vector_type(4))) float f32x4;
typedef __attribute__((ext_vector_type(8))) short bf16x8;

#define DEVINL __device__ __forceinline__

DEVINL float bf2f(u16 u){ union { u32 i; float f; } v; v.i = ((u32)u) << 16; return v.f; }
DEVINL u16 f2bf(float f){
  union { float f; u32 i; } v; v.f = f;
  u32 u = v.i;
  u32 r = (u + 0x7fffu + ((u >> 16) & 1u)) >> 16;   // RNE
  return (u16)r;
}

// async global->LDS, 16B per lane. LDS dest must be wave-uniform base (+lane*16 by HW).
DEVINL void gload16(u16* lds, const void* g){
  __builtin_amdgcn_global_load_lds(
      (__attribute__((address_space(1))) u32*)(g),
      (__attribute__((address_space(3))) u32*)(lds), 16, 0, 0);
}

// ---------------------------------------------------------------------------
// K0: weight transpose + cast: in[K][N] fp32 -> out[N][K] bf16
// ---------------------------------------------------------------------------
__global__ __launch_bounds__(256) void wt_kernel(const float* __restrict__ in,
                                                 u16* __restrict__ out, int K, int N)
{
  __shared__ float tile[64][65];
  int tiles_n = N >> 6;
  int tk = blockIdx.x / tiles_n, tn = blockIdx.x % tiles_n;
  int k0 = tk * 64, n0 = tn * 64;
  int lane = threadIdx.x & 63, wr = threadIdx.x >> 6;
#pragma unroll
  for (int i = 0; i < 16; i++){
    int r = wr * 16 + i;
    tile[r][lane] = in[(size_t)(k0 + r) * N + n0 + lane];
  }
  __syncthreads();
#pragma unroll
  for (int i = 0; i < 16; i++){
    int r = wr * 16 + i;
    out[(size_t)(n0 + r) * K + k0 + lane] = f2bf(tile[lane][r]);
  }
}

// ---------------------------------------------------------------------------
// K1 / K4b: window-gather + LayerNorm.
// MODE 0: out = LN(gather(x))          (K1)
// MODE 1: out = LN(gather(x) + o2)     (K4b; o2 token-major bf16)
// Block = one window (64 tokens x 512 c), 256 threads.
// LDS layout [c][l] with swizzle l ^ (2*(c>>3))&63: conflict-free both phases.
// ---------------------------------------------------------------------------
template<int MODE>
__global__ __launch_bounds__(256) void ln_kernel(
    const float* __restrict__ x, const u16* __restrict__ o2,
    const float* __restrict__ gamma, const float* __restrict__ beta,
    u16* __restrict__ out)
{
  __shared__ u16 sm[512 * 64];
  int wg = blockIdx.x;
  int b = wg >> 8, n = wg & 255, wy = n >> 4, wx = n & 15;
  int t = threadIdx.x, l = t & 63, wv = t >> 6;
  int yy = l >> 3, xx = l & 7;
  size_t xbase = ((size_t)b * 512) * 16384 + (size_t)(wy * 8 + yy) * 128 + wx * 8 + xx;

  // phase A: spatial-coalesced x load -> bf16 LDS (swizzled)
#pragma unroll 4
  for (int i = 0; i < 128; i++){
    int c = wv * 128 + i;
    float v = x[xbase + (size_t)c * 16384];
    sm[c * 64 + (l ^ ((2 * (c >> 3)) & 63))] = f2bf(v);
  }
  __syncthreads();

  // phase B: wave-per-token; lane owns 8 consecutive channels
  size_t gbase = (size_t)wg * 64;
  int lane = l;
  int c0 = lane * 8;
  int fs = (2 * lane) & 63;
  float g8[8], b8[8];
#pragma unroll
  for (int j = 0; j < 8; j++){ g8[j] = gamma[c0 + j]; b8[j] = beta[c0 + j]; }

  for (int it = 0; it < 16; it++){
    int tok = wv * 16 + it;
    int lidx = tok ^ fs;
    u16 oarr[8];
    if (MODE == 1){
      uint4 ov = *(const uint4*)&o2[(gbase + tok) * 512 + c0];
      *(uint4*)oarr = ov;
    }
    float tv[8]; float sum = 0.f, sq = 0.f;
#pragma unroll
    for (int j = 0; j < 8; j++){
      float v = bf2f(sm[(c0 + j) * 64 + lidx]);
      if (MODE == 1) v += bf2f(oarr[j]);
      tv[j] = v; sum += v; sq += v * v;
    }
#pragma unroll
    for (int d = 1; d < 64; d <<= 1){
      sum += __shfl_xor(sum, d, 64);
      sq  += __shfl_xor(sq, d, 64);
    }
    float mu = sum * (1.0f / 512.0f);
    float var = sq * (1.0f / 512.0f) - mu * mu;
    float rs = rsqrtf(var + 1e-5f);
    u16 r8[8];
#pragma unroll
    for (int j = 0; j < 8; j++) r8[j] = f2bf((tv[j] - mu) * rs * g8[j] + b8[j]);
    *(uint4*)&out[(gbase + tok) * 512 + c0] = *(uint4*)r8;
  }
}

// ---------------------------------------------------------------------------
// GEMM: C[M][N](bf16) = A[M][K](bf16) @ BT[N][K](bf16) + bias, epilogues:
// EPI 0: bias only   EPI 1: gelu(v+bias)   EPI 2: v+bias+ADD (bf16 token-major)
// m97 structure: 128x128 tile, BK=32, 4 waves, global_load_lds width 16.
// ---------------------------------------------------------------------------
template<int EPI>
__global__ __launch_bounds__(256) void gemm_kernel(
    const u16* __restrict__ A, const u16* __restrict__ BT,
    const float* __restrict__ bias, const u16* __restrict__ ADD,
    u16* __restrict__ Cout, int M, int N, int K)
{
  (void)M;
  __shared__ u16 As[128 * 32];
  __shared__ u16 Bs[128 * 32];
  const int nbn = N >> 7;
  int bm = blockIdx.x / nbn, bn = blockIdx.x % nbn;
  size_t m0 = (size_t)bm * 128; int n0 = bn * 128;
  int lane = threadIdx.x & 63, wv = threadIdx.x >> 6;
  int wr = wv >> 1, wc = wv & 1;

  f32x4 zero4 = {0.f, 0.f, 0.f, 0.f};
  f32x4 acc[4][4];
#pragma unroll
  for (int i = 0; i < 4; i++)
#pragma unroll
    for (int j = 0; j < 4; j++) acc[i][j] = zero4;

  int srow = wv * 16 + (lane >> 2);
  int skc = (lane & 3) * 8;
  const u16* Abase = A + m0 * K + skc;
  const u16* Bbase = BT + (size_t)n0 * K + skc;

  for (int kt = 0; kt < K; kt += 32){
    gload16(&As[wv * 512],        Abase + (size_t)srow * K + kt);
    gload16(&As[2048 + wv * 512], Abase + (size_t)(srow + 64) * K + kt);
    gload16(&Bs[wv * 512],        Bbase + (size_t)srow * K + kt);
    gload16(&Bs[2048 + wv * 512], Bbase + (size_t)(srow + 64) * K + kt);
    __syncthreads();   // drains vmcnt -> LDS tile ready

    bf16x8 af[4], bfr[4];
    int rb = (lane & 15) * 32 + (lane >> 4) * 8;
#pragma unroll
    for (int mt = 0; mt < 4; mt++) af[mt]  = *(const bf16x8*)&As[(wr * 64 + mt * 16) * 32 + rb];
#pragma unroll
    for (int nt = 0; nt < 4; nt++) bfr[nt] = *(const bf16x8*)&Bs[(wc * 64 + nt * 16) * 32 + rb];
#pragma unroll
    for (int mt = 0; mt < 4; mt++)
#pragma unroll
      for (int nt = 0; nt < 4; nt++)
        acc[mt][nt] = __builtin_amdgcn_mfma_f32_16x16x32_bf16(af[mt], bfr[nt], acc[mt][nt], 0, 0, 0);
    __syncthreads();   // all waves done reading before next stage
  }

  // epilogue: C layout col=lane&15, row=(lane>>4)*4+reg
#pragma unroll
  for (int nt = 0; nt < 4; nt++){
    int c = n0 + wc * 64 + nt * 16 + (lane & 15);
    float bv = bias[c];
#pragma unroll
    for (int mt = 0; mt < 4; mt++){
      size_t r0 = m0 + wr * 64 + mt * 16 + ((lane >> 4) * 4);
#pragma unroll
      for (int reg = 0; reg < 4; reg++){
        float v = acc[mt][nt][reg] + bv;
        if (EPI == 1) v = 0.5f * v * (1.0f + erff(v * 0.70710678118654752f));
        size_t idx = (r0 + reg) * (size_t)N + c;
        if (EPI == 2) v += bf2f(ADD[idx]);
        Cout[idx] = f2bf(v);
      }
    }
  }
}

// ---------------------------------------------------------------------------
// K3: attention per (window, head). 1 wave per block.
// q,k row-major LDS (T2 swizzle); v stored transposed vT[d][m] (swizzled).
// s = (q@k^T)/4096 -> softmax (16-lane shfl reductions) -> p -> o = p@v.
// ---------------------------------------------------------------------------
__global__ __launch_bounds__(64) void attn_kernel(const u16* __restrict__ QKV,
                                                  u16* __restrict__ O)
{
  __shared__ u16 qs[4096], ks2[4096], vs[4096], ps[4096];
  int blk = blockIdx.x;
  int wg = blk >> 3, h = blk & 7;
  size_t g0 = (size_t)wg * 64;
  int lane = threadIdx.x;
  int lr = lane >> 3, lch = lane & 7;

#pragma unroll
  for (int it = 0; it < 8; it++){
    int r = it * 8 + lr;
    int sc = lch ^ (r & 7);
    {
      uint4 d = *(const uint4*)&QKV[(g0 + r) * 1536 + h * 64 + lch * 8];
      *(uint4*)&qs[r * 64 + sc * 8] = d;
    }
    {
      uint4 d = *(const uint4*)&QKV[(g0 + r) * 1536 + 512 + h * 64 + lch * 8];
      *(uint4*)&ks2[r * 64 + sc * 8] = d;
    }
    {
      uint4 d = *(const uint4*)&QKV[(g0 + r) * 1536 + 1024 + h * 64 + lch * 8];
      u16 e[8]; *(uint4*)e = d;
      int m = r;
#pragma unroll
      for (int j = 0; j < 8; j++){
        int dd = lch * 8 + j;
        int off = dd * 64 + ((((m * 2) ^ ((dd & 7) << 4))) >> 1);
        vs[off] = e[j];
      }
    }
  }
  __syncthreads();

  f32x4 zero4 = {0.f, 0.f, 0.f, 0.f};
  f32x4 s[4][4];
#pragma unroll
  for (int i = 0; i < 4; i++)
#pragma unroll
    for (int j = 0; j < 4; j++) s[i][j] = zero4;

#pragma unroll
  for (int ks = 0; ks < 2; ks++){
    bf16x8 aq[4], bk[4];
#pragma unroll
    for (int mt = 0; mt < 4; mt++){
      int r = mt * 16 + (lane & 15);
      int cb = (ks * 64 + (lane >> 4) * 16) ^ ((r & 7) << 4);
      aq[mt] = *(const bf16x8*)&qs[r * 64 + (cb >> 1)];
    }
#pragma unroll
    for (int nt = 0; nt < 4; nt++){
      int r = nt * 16 + (lane & 15);
      int cb = (ks * 64 + (lane >> 4) * 16) ^ ((r & 7) << 4);
      bk[nt] = *(const bf16x8*)&ks2[r * 64 + (cb >> 1)];
    }
#pragma unroll
    for (int mt = 0; mt < 4; mt++)
#pragma unroll
      for (int nt = 0; nt < 4; nt++)
        s[mt][nt] = __builtin_amdgcn_mfma_f32_16x16x32_bf16(aq[mt], bk[nt], s[mt][nt], 0, 0, 0);
  }

  const float scl = 1.0f / 4096.0f;
#pragma unroll
  for (int mt = 0; mt < 4; mt++){
#pragma unroll
    for (int reg = 0; reg < 4; reg++){
      float mx = -1e30f;
#pragma unroll
      for (int nt = 0; nt < 4; nt++){
        float v = s[mt][nt][reg] * scl; s[mt][nt][reg] = v; mx = fmaxf(mx, v);
      }
#pragma unroll
      for (int d = 1; d < 16; d <<= 1) mx = fmaxf(mx, __shfl_xor(mx, d, 64));
      float sum = 0.f;
#pragma unroll
      for (int nt = 0; nt < 4; nt++){
        float e = __expf(s[mt][nt][reg] - mx); s[mt][nt][reg] = e; sum += e;
      }
#pragma unroll
      for (int d = 1; d < 16; d <<= 1) sum += __shfl_xor(sum, d, 64);
      float inv = 1.0f / sum;
#pragma unroll
      for (int nt = 0; nt < 4; nt++) s[mt][nt][reg] *= inv;
    }
  }

  // p -> LDS (A-matrix layout, swizzled)
#pragma unroll
  for (int mt = 0; mt < 4; mt++)
#pragma unroll
    for (int reg = 0; reg < 4; reg++){
      int r = mt * 16 + ((lane >> 4) * 4) + reg;
#pragma unroll
      for (int nt = 0; nt < 4; nt++){
        int c = nt * 16 + (lane & 15);
        ps[r * 64 + ((((c * 2) ^ ((r & 7) << 4))) >> 1)] = f2bf(s[mt][nt][reg]);
      }
    }
  __syncthreads();

  f32x4 o[4][4];
#pragma unroll
  for (int i = 0; i < 4; i++)
#pragma unroll
    for (int j = 0; j < 4; j++) o[i][j] = zero4;

#pragma unroll
  for (int ks = 0; ks < 2; ks++){
    bf16x8 ap[4], bv[4];
#pragma unroll
    for (int mt = 0; mt < 4; mt++){
      int r = mt * 16 + (lane & 15);
      int cb = (ks * 64 + (lane >> 4) * 16) ^ ((r & 7) << 4);
      ap[mt] = *(const bf16x8*)&ps[r * 64 + (cb >> 1)];
    }
#pragma unroll
    for (int nt = 0; nt < 4; nt++){
      int dd = nt * 16 + (lane & 15);
      int cb = (ks * 64 + (lane >> 4) * 16) ^ ((dd & 7) << 4);
      bv[nt] = *(const bf16x8*)&vs[dd * 64 + (cb >> 1)];
    }
#pragma unroll
    for (int mt = 0; mt < 4; mt++)
#pragma unroll
      for (int nt = 0; nt < 4; nt++)
        o[mt][nt] = __builtin_amdgcn_mfma_f32_16x16x32_bf16(ap[mt], bv[nt], o[mt][nt], 0, 0, 0);
  }

#pragma unroll
  for (int mt = 0; mt < 4; mt++)
#pragma unroll
    for (int reg = 0; reg < 4; reg++){
      size_t l = mt * 16 + ((lane >> 4) * 4) + reg;
#pragma unroll
      for (int nt = 0; nt < 4; nt++){
        int dd = nt * 16 + (lane & 15);
        O[(g0 + l) * 512 + h * 64 + dd] = f2bf(o[mt][nt][reg]);
      }
    }
}

// ---------------------------------------------------------------------------
// K7: y = x + scatter(MS). Mirror of K1.
// ---------------------------------------------------------------------------
__global__ __launch_bounds__(256) void scatter_kernel(
    const float* __restrict__ x, const u16* __restrict__ ms, float* __restrict__ y)
{
  __shared__ u16 sm[512 * 64];
  int wg = blockIdx.x;
  int b = wg >> 8, n = wg & 255, wy = n >> 4, wx = n & 15;
  int t = threadIdx.x, lane = t & 63, wv = t >> 6;
  size_t gbase = (size_t)wg * 64;
  int c0 = lane * 8, fs = (2 * lane) & 63;

  for (int it = 0; it < 16; it++){
    int tok = wv * 16 + it;
    uint4 d = *(const uint4*)&ms[(gbase + tok) * 512 + c0];
    u16 e[8]; *(uint4*)e = d;
    int lidx = tok ^ fs;
#pragma unroll
    for (int j = 0; j < 8; j++) sm[(c0 + j) * 64 + lidx] = e[j];
  }
  __syncthreads();

  int l = lane; int yy = l >> 3, xx = l & 7;
  size_t xbase = ((size_t)b * 512) * 16384 + (size_t)(wy * 8 + yy) * 128 + wx * 8 + xx;
#pragma unroll 4
  for (int i = 0; i < 128; i++){
    int c = wv * 128 + i;
    size_t a = xbase + (size_t)c * 16384;
    y[a] = x[a] + bf2f(sm[c * 64 + (l ^ ((2 * (c >> 3)) & 63))]);
  }
}

// ---------------------------------------------------------------------------
extern "C" void kernel_launch(void* const* d_in, const int* in_sizes, int n_in,
                              void* d_out, int out_size, void* d_ws, size_t ws_size,
                              hipStream_t stream)
{
  (void)in_sizes; (void)n_in; (void)out_size; (void)ws_size;
  const float* x      = (const float*)d_in[0];
  const float* gamma1 = (const float*)d_in[1];
  const float* beta1  = (const float*)d_in[2];
  const float* gamma2 = (const float*)d_in[3];
  const float* beta2  = (const float*)d_in[4];
  const float* w_qkv  = (const float*)d_in[5];
  const float* b_qkv  = (const float*)d_in[6];
  const float* w_out  = (const float*)d_in[7];
  const float* b_out  = (const float*)d_in[8];
  const float* w1     = (const float*)d_in[9];
  const float* b1     = (const float*)d_in[10];
  const float* w2     = (const float*)d_in[11];
  const float* b2     = (const float*)d_in[12];
  float* y = (float*)d_out;

  char* ws = (char*)d_ws;
  // workspace layout (bytes)
  u16* WqkvT = (u16*)(ws + 0);          // 1536x512  bf16  (1.5 MB)
  u16* WoutT = (u16*)(ws + 1572864);    // 512x512
  u16* W1T   = (u16*)(ws + 2097152);    // 2048x512
  u16* W2T   = (u16*)(ws + 4194304);    // 512x2048
  u16* XN    = (u16*)(ws + 6291456);    // 131072x512 bf16 (134 MB) -- xn then xn2
  u16* O2    = (u16*)(ws + 140509184);  // 131072x512 bf16 (134 MB) -- attn branch out
  u16* Obuf  = (u16*)(ws + 274726912);  // 131072x512 bf16 (134 MB) -- attn concat, reused as MS
  u16* QKV   = (u16*)(ws + 408944640);  // max(QKV 402MB, H 537MB)
  u16* Hbuf  = QKV;
  u16* MS    = Obuf;
  const int M = 131072;

  // K0: weight prep
  wt_kernel<<<8 * 24, 256, 0, stream>>>(w_qkv, WqkvT, 512, 1536);
  wt_kernel<<<8 * 8,  256, 0, stream>>>(w_out, WoutT, 512, 512);
  wt_kernel<<<8 * 32, 256, 0, stream>>>(w1, W1T, 512, 2048);
  wt_kernel<<<32 * 8, 256, 0, stream>>>(w2, W2T, 2048, 512);

  // K1: LN1 + gather
  ln_kernel<0><<<2048, 256, 0, stream>>>(x, nullptr, gamma1, beta1, XN);
  // K2: QKV projection
  gemm_kernel<0><<<(M / 128) * (1536 / 128), 256, 0, stream>>>(XN, WqkvT, b_qkv, nullptr, QKV, M, 1536, 512);
  // K3: attention
  attn_kernel<<<16384, 64, 0, stream>>>(QKV, Obuf);
  // K4a: out-proj
  gemm_kernel<0><<<(M / 128) * (512 / 128), 256, 0, stream>>>(Obuf, WoutT, b_out, nullptr, O2, M, 512, 512);
  // K4b: LN2 (gather(x) + o2)
  ln_kernel<1><<<2048, 256, 0, stream>>>(x, O2, gamma2, beta2, XN);
  // K5: MLP up + GELU
  gemm_kernel<1><<<(M / 128) * (2048 / 128), 256, 0, stream>>>(XN, W1T, b1, nullptr, Hbuf, M, 2048, 512);
  // K6: MLP down + b2 + o2
  gemm_kernel<2><<<(M / 128) * (512 / 128), 256, 0, stream>>>(Hbuf, W2T, b2, O2, MS, M, 512, 2048);
  // K7: scatter + final residual with fp32 x
  scatter_kernel<<<2048, 256, 0, stream>>>(x, MS, y);
}

// Round 3
// 2457.498 us; speedup vs baseline: 1.1755x; 1.1755x over previous
//
#include <hip/hip_runtime.h>
#include <cstdint>
#include <cstddef>

// ============================================================================
// Swin-style window-attention block, MI355X (gfx950).
// R3: R2 GEMM pipeline with CORRECTED swizzle. BK=32 rows have only 4 x 16B
// slots, so the XOR swizzle is 2-bit: g(row)=(row>>1)&3 (R2's (row&7)<<3
// escaped the row -> wrong data). Stage applies the same involution to the
// per-lane GLOBAL column (linear global_load_lds dest); fragment reads apply
// it to the slot index. Wave64 b128 reads now hit every 16B granule exactly
// 8 times -> conflict-free throughput.
// ============================================================================

typedef unsigned short u16;
typedef unsigned int u32;
typedef __attribute__((ext_vector_type(4))) float f32x4;
typedef __attribute__((ext_vector_type(8))) short bf16x8;

#define DEVINL __device__ __forceinline__

DEVINL float bf2f(u16 u){ union { u32 i; float f; } v; v.i = ((u32)u) << 16; return v.f; }
DEVINL u16 f2bf(float f){
  union { float f; u32 i; } v; v.f = f;
  u32 u = v.i;
  u32 r = (u + 0x7fffu + ((u >> 16) & 1u)) >> 16;   // RNE
  return (u16)r;
}

// async global->LDS, 16B per lane. LDS dest is wave-uniform base (+lane*16 by HW).
DEVINL void gload16(u16* lds, const void* g){
  __builtin_amdgcn_global_load_lds(
      (__attribute__((address_space(1))) u32*)(g),
      (__attribute__((address_space(3))) u32*)(lds), 16, 0, 0);
}

// ---------------------------------------------------------------------------
// K0: weight transpose + cast: in[K][N] fp32 -> out[N][K] bf16
// ---------------------------------------------------------------------------
__global__ __launch_bounds__(256) void wt_kernel(const float* __restrict__ in,
                                                 u16* __restrict__ out, int K, int N)
{
  __shared__ float tile[64][65];
  int tiles_n = N >> 6;
  int tk = blockIdx.x / tiles_n, tn = blockIdx.x % tiles_n;
  int k0 = tk * 64, n0 = tn * 64;
  int lane = threadIdx.x & 63, wr = threadIdx.x >> 6;
#pragma unroll
  for (int i = 0; i < 16; i++){
    int r = wr * 16 + i;
    tile[r][lane] = in[(size_t)(k0 + r) * N + n0 + lane];
  }
  __syncthreads();
#pragma unroll
  for (int i = 0; i < 16; i++){
    int r = wr * 16 + i;
    out[(size_t)(n0 + r) * K + k0 + lane] = f2bf(tile[lane][r]);
  }
}

// ---------------------------------------------------------------------------
// K1 / K4b: window-gather + LayerNorm.
// MODE 0: out = LN(gather(x))          (K1)
// MODE 1: out = LN(gather(x) + o2)     (K4b; o2 token-major bf16)
// ---------------------------------------------------------------------------
template<int MODE>
__global__ __launch_bounds__(256) void ln_kernel(
    const float* __restrict__ x, const u16* __restrict__ o2,
    const float* __restrict__ gamma, const float* __restrict__ beta,
    u16* __restrict__ out)
{
  __shared__ u16 sm[512 * 64];
  int wg = blockIdx.x;
  int b = wg >> 8, n = wg & 255, wy = n >> 4, wx = n & 15;
  int t = threadIdx.x, l = t & 63, wv = t >> 6;
  int yy = l >> 3, xx = l & 7;
  size_t xbase = ((size_t)b * 512) * 16384 + (size_t)(wy * 8 + yy) * 128 + wx * 8 + xx;

#pragma unroll 4
  for (int i = 0; i < 128; i++){
    int c = wv * 128 + i;
    float v = x[xbase + (size_t)c * 16384];
    sm[c * 64 + (l ^ ((2 * (c >> 3)) & 63))] = f2bf(v);
  }
  __syncthreads();

  size_t gbase = (size_t)wg * 64;
  int lane = l;
  int c0 = lane * 8;
  int fs = (2 * lane) & 63;
  float g8[8], b8[8];
#pragma unroll
  for (int j = 0; j < 8; j++){ g8[j] = gamma[c0 + j]; b8[j] = beta[c0 + j]; }

  for (int it = 0; it < 16; it++){
    int tok = wv * 16 + it;
    int lidx = tok ^ fs;
    u16 oarr[8];
    if (MODE == 1){
      uint4 ov = *(const uint4*)&o2[(gbase + tok) * 512 + c0];
      *(uint4*)oarr = ov;
    }
    float tv[8]; float sum = 0.f, sq = 0.f;
#pragma unroll
    for (int j = 0; j < 8; j++){
      float v = bf2f(sm[(c0 + j) * 64 + lidx]);
      if (MODE == 1) v += bf2f(oarr[j]);
      tv[j] = v; sum += v; sq += v * v;
    }
#pragma unroll
    for (int d = 1; d < 64; d <<= 1){
      sum += __shfl_xor(sum, d, 64);
      sq  += __shfl_xor(sq, d, 64);
    }
    float mu = sum * (1.0f / 512.0f);
    float var = sq * (1.0f / 512.0f) - mu * mu;
    float rs = rsqrtf(var + 1e-5f);
    u16 r8[8];
#pragma unroll
    for (int j = 0; j < 8; j++) r8[j] = f2bf((tv[j] - mu) * rs * g8[j] + b8[j]);
    *(uint4*)&out[(gbase + tok) * 512 + c0] = *(uint4*)r8;
  }
}

// ---------------------------------------------------------------------------
// GEMM: C[M][N](bf16) = A[M][K](bf16) @ BT[N][K](bf16) + bias
// EPI 0: bias   EPI 1: fast-gelu(v+bias)   EPI 2: v+bias+ADD (coalesced)
// 128x128 tile, BK=32, 4 waves. 2-phase double-buffered pipeline.
// LDS 32 KB: As0|Bs0|As1|Bs1 (4096 u16 each), reused as C[128][128] in epilogue.
// Swizzle (in-row, 4 slots of 8 u16): slot' = slot ^ ((row>>1)&3).
// ---------------------------------------------------------------------------
template<int EPI>
__global__ __launch_bounds__(256) void gemm_kernel(
    const u16* __restrict__ A, const u16* __restrict__ BT,
    const float* __restrict__ bias, const u16* __restrict__ ADD,
    u16* __restrict__ Cout, int N, int K)
{
  __shared__ u16 smem[16384];
  const int nbn = N >> 7;
  int nwg = gridDim.x;
  int bid = blockIdx.x;
  int wgid = (bid & 7) * (nwg >> 3) + (bid >> 3);   // XCD-chunked swizzle (nwg%8==0)
  int bm = wgid / nbn, bn = wgid % nbn;
  size_t m0 = (size_t)bm * 128; int n0 = bn * 128;
  int lane = threadIdx.x & 63, wv = threadIdx.x >> 6;
  int wr = wv >> 1, wc = wv & 1;

  f32x4 zero4 = {0.f, 0.f, 0.f, 0.f};
  f32x4 acc[4][4];
#pragma unroll
  for (int i = 0; i < 4; i++)
#pragma unroll
    for (int j = 0; j < 4; j++) acc[i][j] = zero4;

  // staging: wave wv covers rows [wv*16, wv*16+16) of each 64-row half.
  // gload_lds dest is linear (lane*16B): row = wv*16 + (lane>>2), stored slot
  // sp = lane&3. Source column = 8*(sp ^ g(row)), g(row) = (row>>1)&3.
  int srow = wv * 16 + (lane >> 2);
  int scol = (((lane & 3) ^ ((srow >> 1) & 3)) * 8);
  const u16* Abase = A + m0 * (size_t)K;
  const u16* Bbase = BT + (size_t)n0 * K;

  auto STAGE = [&](int buf, int kt){
    u16* as = &smem[buf * 8192];
    u16* bs = as + 4096;
    gload16(as + wv * 512,        Abase + (size_t)srow * K + kt + scol);
    gload16(as + 2048 + wv * 512, Abase + (size_t)(srow + 64) * K + kt + scol);
    gload16(bs + wv * 512,        Bbase + (size_t)srow * K + kt + scol);
    gload16(bs + 2048 + wv * 512, Bbase + (size_t)(srow + 64) * K + kt + scol);
  };

  STAGE(0, 0);
  __syncthreads();                      // prologue: wait tile 0

  int nsteps = K >> 5;
  int cur = 0;
  int kslot = lane >> 4;                // k-slot (8 u16 each)
  for (int t = 0; t < nsteps; ++t){
    if (t + 1 < nsteps) STAGE(cur ^ 1, (t + 1) << 5);   // issue next FIRST
    const u16* as = &smem[cur * 8192];
    const u16* bs = as + 4096;
    bf16x8 af[4], bfr[4];
#pragma unroll
    for (int mt = 0; mt < 4; mt++){
      int row = wr * 64 + mt * 16 + (lane & 15);
      af[mt] = *(const bf16x8*)&as[row * 32 + ((kslot ^ ((row >> 1) & 3)) * 8)];
    }
#pragma unroll
    for (int nt = 0; nt < 4; nt++){
      int row = wc * 64 + nt * 16 + (lane & 15);
      bfr[nt] = *(const bf16x8*)&bs[row * 32 + ((kslot ^ ((row >> 1) & 3)) * 8)];
    }
#pragma unroll
    for (int mt = 0; mt < 4; mt++)
#pragma unroll
      for (int nt = 0; nt < 4; nt++)
        acc[mt][nt] = __builtin_amdgcn_mfma_f32_16x16x32_bf16(af[mt], bfr[nt], acc[mt][nt], 0, 0, 0);
    __syncthreads();                    // drains vmcnt (next tile landed during MFMA)
    cur ^= 1;
  }

  // ---- epilogue phase 1: acc -> LDS C[128][128] (swizzled), bias/act applied
#pragma unroll
  for (int nt = 0; nt < 4; nt++){
    int cc = wc * 64 + nt * 16 + (lane & 15);
    float bv = bias[n0 + cc];
#pragma unroll
    for (int mt = 0; mt < 4; mt++){
      int r0 = wr * 64 + mt * 16 + ((lane >> 4) * 4);
#pragma unroll
      for (int reg = 0; reg < 4; reg++){
        int rr = r0 + reg;
        float v = acc[mt][nt][reg] + bv;
        if (EPI == 1){
          // tanh-form GELU: h*sigmoid(1.5957691*(h+0.044715h^3)); |err|<~4e-4
          float h2 = v * v;
          float z = -1.5957691216057308f * (v + 0.044715f * v * h2);
          float e = __expf(z);
          v = v * __builtin_amdgcn_rcpf(1.0f + e);
        }
        smem[rr * 128 + (cc ^ ((rr & 7) << 3))] = f2bf(v);
      }
    }
  }
  __syncthreads();

  // ---- epilogue phase 2: coalesced full-line stores (+ coalesced ADD for EPI2)
  int tr = threadIdx.x >> 2;            // row within 64-row half
  int tc = threadIdx.x & 3;             // 16B slot
#pragma unroll
  for (int i = 0; i < 2; i++){
    int r = i * 64 + tr;
    size_t gro = (m0 + r) * (size_t)N + n0;
#pragma unroll
    for (int j = 0; j < 4; j++){
      int cw = tc * 8 + j * 32;         // u16 col in [0,128)
      uint4 d = *(const uint4*)&smem[r * 128 + (cw ^ ((r & 7) << 3))];
      if (EPI == 2){
        uint4 av = *(const uint4*)&ADD[gro + cw];
        u16 de[8], ae[8];
        *(uint4*)de = d; *(uint4*)ae = av;
#pragma unroll
        for (int k = 0; k < 8; k++) de[k] = f2bf(bf2f(de[k]) + bf2f(ae[k]));
        d = *(uint4*)de;
      }
      *(uint4*)&Cout[gro + cw] = d;
    }
  }
}

// ---------------------------------------------------------------------------
// K3: attention per (window, head). 1 wave per block. (unchanged)
// ---------------------------------------------------------------------------
__global__ __launch_bounds__(64) void attn_kernel(const u16* __restrict__ QKV,
                                                  u16* __restrict__ O)
{
  __shared__ u16 qs[4096], ks2[4096], vs[4096], ps[4096];
  int blk = blockIdx.x;
  int wg = blk >> 3, h = blk & 7;
  size_t g0 = (size_t)wg * 64;
  int lane = threadIdx.x;
  int lr = lane >> 3, lch = lane & 7;

#pragma unroll
  for (int it = 0; it < 8; it++){
    int r = it * 8 + lr;
    int sc = lch ^ (r & 7);
    {
      uint4 d = *(const uint4*)&QKV[(g0 + r) * 1536 + h * 64 + lch * 8];
      *(uint4*)&qs[r * 64 + sc * 8] = d;
    }
    {
      uint4 d = *(const uint4*)&QKV[(g0 + r) * 1536 + 512 + h * 64 + lch * 8];
      *(uint4*)&ks2[r * 64 + sc * 8] = d;
    }
    {
      uint4 d = *(const uint4*)&QKV[(g0 + r) * 1536 + 1024 + h * 64 + lch * 8];
      u16 e[8]; *(uint4*)e = d;
      int m = r;
#pragma unroll
      for (int j = 0; j < 8; j++){
        int dd = lch * 8 + j;
        int off = dd * 64 + ((((m * 2) ^ ((dd & 7) << 4))) >> 1);
        vs[off] = e[j];
      }
    }
  }
  __syncthreads();

  f32x4 zero4 = {0.f, 0.f, 0.f, 0.f};
  f32x4 s[4][4];
#pragma unroll
  for (int i = 0; i < 4; i++)
#pragma unroll
    for (int j = 0; j < 4; j++) s[i][j] = zero4;

#pragma unroll
  for (int ks = 0; ks < 2; ks++){
    bf16x8 aq[4], bk[4];
#pragma unroll
    for (int mt = 0; mt < 4; mt++){
      int r = mt * 16 + (lane & 15);
      int cb = (ks * 64 + (lane >> 4) * 16) ^ ((r & 7) << 4);
      aq[mt] = *(const bf16x8*)&qs[r * 64 + (cb >> 1)];
    }
#pragma unroll
    for (int nt = 0; nt < 4; nt++){
      int r = nt * 16 + (lane & 15);
      int cb = (ks * 64 + (lane >> 4) * 16) ^ ((r & 7) << 4);
      bk[nt] = *(const bf16x8*)&ks2[r * 64 + (cb >> 1)];
    }
#pragma unroll
    for (int mt = 0; mt < 4; mt++)
#pragma unroll
      for (int nt = 0; nt < 4; nt++)
        s[mt][nt] = __builtin_amdgcn_mfma_f32_16x16x32_bf16(aq[mt], bk[nt], s[mt][nt], 0, 0, 0);
  }

  const float scl = 1.0f / 4096.0f;
#pragma unroll
  for (int mt = 0; mt < 4; mt++){
#pragma unroll
    for (int reg = 0; reg < 4; reg++){
      float mx = -1e30f;
#pragma unroll
      for (int nt = 0; nt < 4; nt++){
        float v = s[mt][nt][reg] * scl; s[mt][nt][reg] = v; mx = fmaxf(mx, v);
      }
#pragma unroll
      for (int d = 1; d < 16; d <<= 1) mx = fmaxf(mx, __shfl_xor(mx, d, 64));
      float sum = 0.f;
#pragma unroll
      for (int nt = 0; nt < 4; nt++){
        float e = __expf(s[mt][nt][reg] - mx); s[mt][nt][reg] = e; sum += e;
      }
#pragma unroll
      for (int d = 1; d < 16; d <<= 1) sum += __shfl_xor(sum, d, 64);
      float inv = 1.0f / sum;
#pragma unroll
      for (int nt = 0; nt < 4; nt++) s[mt][nt][reg] *= inv;
    }
  }

#pragma unroll
  for (int mt = 0; mt < 4; mt++)
#pragma unroll
    for (int reg = 0; reg < 4; reg++){
      int r = mt * 16 + ((lane >> 4) * 4) + reg;
#pragma unroll
      for (int nt = 0; nt < 4; nt++){
        int c = nt * 16 + (lane & 15);
        ps[r * 64 + ((((c * 2) ^ ((r & 7) << 4))) >> 1)] = f2bf(s[mt][nt][reg]);
      }
    }
  __syncthreads();

  f32x4 o[4][4];
#pragma unroll
  for (int i = 0; i < 4; i++)
#pragma unroll
    for (int j = 0; j < 4; j++) o[i][j] = zero4;

#pragma unroll
  for (int ks = 0; ks < 2; ks++){
    bf16x8 ap[4], bv[4];
#pragma unroll
    for (int mt = 0; mt < 4; mt++){
      int r = mt * 16 + (lane & 15);
      int cb = (ks * 64 + (lane >> 4) * 16) ^ ((r & 7) << 4);
      ap[mt] = *(const bf16x8*)&ps[r * 64 + (cb >> 1)];
    }
#pragma unroll
    for (int nt = 0; nt < 4; nt++){
      int dd = nt * 16 + (lane & 15);
      int cb = (ks * 64 + (lane >> 4) * 16) ^ ((dd & 7) << 4);
      bv[nt] = *(const bf16x8*)&vs[dd * 64 + (cb >> 1)];
    }
#pragma unroll
    for (int mt = 0; mt < 4; mt++)
#pragma unroll
      for (int nt = 0; nt < 4; nt++)
        o[mt][nt] = __builtin_amdgcn_mfma_f32_16x16x32_bf16(ap[mt], bv[nt], o[mt][nt], 0, 0, 0);
  }

#pragma unroll
  for (int mt = 0; mt < 4; mt++)
#pragma unroll
    for (int reg = 0; reg < 4; reg++){
      size_t l = mt * 16 + ((lane >> 4) * 4) + reg;
#pragma unroll
      for (int nt = 0; nt < 4; nt++){
        int dd = nt * 16 + (lane & 15);
        O[(g0 + l) * 512 + h * 64 + dd] = f2bf(o[mt][nt][reg]);
      }
    }
}

// ---------------------------------------------------------------------------
// K7: y = x + scatter(MS). (unchanged)
// ---------------------------------------------------------------------------
__global__ __launch_bounds__(256) void scatter_kernel(
    const float* __restrict__ x, const u16* __restrict__ ms, float* __restrict__ y)
{
  __shared__ u16 sm[512 * 64];
  int wg = blockIdx.x;
  int b = wg >> 8, n = wg & 255, wy = n >> 4, wx = n & 15;
  int t = threadIdx.x, lane = t & 63, wv = t >> 6;
  size_t gbase = (size_t)wg * 64;
  int c0 = lane * 8, fs = (2 * lane) & 63;

  for (int it = 0; it < 16; it++){
    int tok = wv * 16 + it;
    uint4 d = *(const uint4*)&ms[(gbase + tok) * 512 + c0];
    u16 e[8]; *(uint4*)e = d;
    int lidx = tok ^ fs;
#pragma unroll
    for (int j = 0; j < 8; j++) sm[(c0 + j) * 64 + lidx] = e[j];
  }
  __syncthreads();

  int l = lane; int yy = l >> 3, xx = l & 7;
  size_t xbase = ((size_t)b * 512) * 16384 + (size_t)(wy * 8 + yy) * 128 + wx * 8 + xx;
#pragma unroll 4
  for (int i = 0; i < 128; i++){
    int c = wv * 128 + i;
    size_t a = xbase + (size_t)c * 16384;
    y[a] = x[a] + bf2f(sm[c * 64 + (l ^ ((2 * (c >> 3)) & 63))]);
  }
}

// ---------------------------------------------------------------------------
extern "C" void kernel_launch(void* const* d_in, const int* in_sizes, int n_in,
                              void* d_out, int out_size, void* d_ws, size_t ws_size,
                              hipStream_t stream)
{
  (void)in_sizes; (void)n_in; (void)out_size; (void)ws_size;
  const float* x      = (const float*)d_in[0];
  const float* gamma1 = (const float*)d_in[1];
  const float* beta1  = (const float*)d_in[2];
  const float* gamma2 = (const float*)d_in[3];
  const float* beta2  = (const float*)d_in[4];
  const float* w_qkv  = (const float*)d_in[5];
  const float* b_qkv  = (const float*)d_in[6];
  const float* w_out  = (const float*)d_in[7];
  const float* b_out  = (const float*)d_in[8];
  const float* w1     = (const float*)d_in[9];
  const float* b1     = (const float*)d_in[10];
  const float* w2     = (const float*)d_in[11];
  const float* b2     = (const float*)d_in[12];
  float* y = (float*)d_out;

  char* ws = (char*)d_ws;
  u16* WqkvT = (u16*)(ws + 0);          // 1536x512  bf16
  u16* WoutT = (u16*)(ws + 1572864);    // 512x512
  u16* W1T   = (u16*)(ws + 2097152);    // 2048x512
  u16* W2T   = (u16*)(ws + 4194304);    // 512x2048
  u16* XN    = (u16*)(ws + 6291456);    // 131072x512 bf16
  u16* O2    = (u16*)(ws + 140509184);  // 131072x512 bf16
  u16* Obuf  = (u16*)(ws + 274726912);  // 131072x512 bf16 (attn out, reused as MS)
  u16* QKV   = (u16*)(ws + 408944640);  // max(QKV 402MB, H 537MB)
  u16* Hbuf  = QKV;
  u16* MS    = Obuf;
  const int M = 131072;

  wt_kernel<<<8 * 24, 256, 0, stream>>>(w_qkv, WqkvT, 512, 1536);
  wt_kernel<<<8 * 8,  256, 0, stream>>>(w_out, WoutT, 512, 512);
  wt_kernel<<<8 * 32, 256, 0, stream>>>(w1, W1T, 512, 2048);
  wt_kernel<<<32 * 8, 256, 0, stream>>>(w2, W2T, 2048, 512);

  ln_kernel<0><<<2048, 256, 0, stream>>>(x, nullptr, gamma1, beta1, XN);
  gemm_kernel<0><<<(M / 128) * (1536 / 128), 256, 0, stream>>>(XN, WqkvT, b_qkv, nullptr, QKV, 1536, 512);
  attn_kernel<<<16384, 64, 0, stream>>>(QKV, Obuf);
  gemm_kernel<0><<<(M / 128) * (512 / 128), 256, 0, stream>>>(Obuf, WoutT, b_out, nullptr, O2, 512, 512);
  ln_kernel<1><<<2048, 256, 0, stream>>>(x, O2, gamma2, beta2, XN);
  gemm_kernel<1><<<(M / 128) * (2048 / 128), 256, 0, stream>>>(XN, W1T, b1, nullptr, Hbuf, 2048, 512);
  gemm_kernel<2><<<(M / 128) * (512 / 128), 256, 0, stream>>>(Hbuf, W2T, b2, O2, MS, 512, 2048);
  scatter_kernel<<<2048, 256, 0, stream>>>(x, MS, y);
}

// Round 4
// 2361.508 us; speedup vs baseline: 1.2233x; 1.0406x over previous
//
#include <hip/hip_runtime.h>
#include <cstdint>
#include <cstddef>

// ============================================================================
// Swin-style window-attention block, MI355X (gfx950).
// R4: GEMM -> 256x256 tile, 8 waves, 4-slot LDS ring (BK=32/slot), counted
// vmcnt(8) (T4, never drains in-loop), raw s_barrier, setprio around MFMA.
// Stage for K-step t+3 issued right after the barrier of step t (slot freed
// at t-1). Epilogue reuses the 128KB LDS as the 256^2 C tile (coalesced).
// LN / attention / scatter unchanged (to be measured this round).
// ============================================================================

typedef unsigned short u16;
typedef unsigned int u32;
typedef __attribute__((ext_vector_type(4))) float f32x4;
typedef __attribute__((ext_vector_type(8))) short bf16x8;

#define DEVINL __device__ __forceinline__

DEVINL float bf2f(u16 u){ union { u32 i; float f; } v; v.i = ((u32)u) << 16; return v.f; }
DEVINL u16 f2bf(float f){
  union { float f; u32 i; } v; v.f = f;
  u32 u = v.i;
  u32 r = (u + 0x7fffu + ((u >> 16) & 1u)) >> 16;   // RNE
  return (u16)r;
}

// async global->LDS, 16B per lane. LDS dest is wave-uniform base (+lane*16 by HW).
DEVINL void gload16(u16* lds, const void* g){
  __builtin_amdgcn_global_load_lds(
      (__attribute__((address_space(1))) u32*)(g),
      (__attribute__((address_space(3))) u32*)(lds), 16, 0, 0);
}

// ---------------------------------------------------------------------------
// K0: weight transpose + cast: in[K][N] fp32 -> out[N][K] bf16
// ---------------------------------------------------------------------------
__global__ __launch_bounds__(256) void wt_kernel(const float* __restrict__ in,
                                                 u16* __restrict__ out, int K, int N)
{
  __shared__ float tile[64][65];
  int tiles_n = N >> 6;
  int tk = blockIdx.x / tiles_n, tn = blockIdx.x % tiles_n;
  int k0 = tk * 64, n0 = tn * 64;
  int lane = threadIdx.x & 63, wr = threadIdx.x >> 6;
#pragma unroll
  for (int i = 0; i < 16; i++){
    int r = wr * 16 + i;
    tile[r][lane] = in[(size_t)(k0 + r) * N + n0 + lane];
  }
  __syncthreads();
#pragma unroll
  for (int i = 0; i < 16; i++){
    int r = wr * 16 + i;
    out[(size_t)(n0 + r) * K + k0 + lane] = f2bf(tile[lane][r]);
  }
}

// ---------------------------------------------------------------------------
// K1 / K4b: window-gather + LayerNorm. (unchanged)
// ---------------------------------------------------------------------------
template<int MODE>
__global__ __launch_bounds__(256) void ln_kernel(
    const float* __restrict__ x, const u16* __restrict__ o2,
    const float* __restrict__ gamma, const float* __restrict__ beta,
    u16* __restrict__ out)
{
  __shared__ u16 sm[512 * 64];
  int wg = blockIdx.x;
  int b = wg >> 8, n = wg & 255, wy = n >> 4, wx = n & 15;
  int t = threadIdx.x, l = t & 63, wv = t >> 6;
  int yy = l >> 3, xx = l & 7;
  size_t xbase = ((size_t)b * 512) * 16384 + (size_t)(wy * 8 + yy) * 128 + wx * 8 + xx;

#pragma unroll 4
  for (int i = 0; i < 128; i++){
    int c = wv * 128 + i;
    float v = x[xbase + (size_t)c * 16384];
    sm[c * 64 + (l ^ ((2 * (c >> 3)) & 63))] = f2bf(v);
  }
  __syncthreads();

  size_t gbase = (size_t)wg * 64;
  int lane = l;
  int c0 = lane * 8;
  int fs = (2 * lane) & 63;
  float g8[8], b8[8];
#pragma unroll
  for (int j = 0; j < 8; j++){ g8[j] = gamma[c0 + j]; b8[j] = beta[c0 + j]; }

  for (int it = 0; it < 16; it++){
    int tok = wv * 16 + it;
    int lidx = tok ^ fs;
    u16 oarr[8];
    if (MODE == 1){
      uint4 ov = *(const uint4*)&o2[(gbase + tok) * 512 + c0];
      *(uint4*)oarr = ov;
    }
    float tv[8]; float sum = 0.f, sq = 0.f;
#pragma unroll
    for (int j = 0; j < 8; j++){
      float v = bf2f(sm[(c0 + j) * 64 + lidx]);
      if (MODE == 1) v += bf2f(oarr[j]);
      tv[j] = v; sum += v; sq += v * v;
    }
#pragma unroll
    for (int d = 1; d < 64; d <<= 1){
      sum += __shfl_xor(sum, d, 64);
      sq  += __shfl_xor(sq, d, 64);
    }
    float mu = sum * (1.0f / 512.0f);
    float var = sq * (1.0f / 512.0f) - mu * mu;
    float rs = rsqrtf(var + 1e-5f);
    u16 r8[8];
#pragma unroll
    for (int j = 0; j < 8; j++) r8[j] = f2bf((tv[j] - mu) * rs * g8[j] + b8[j]);
    *(uint4*)&out[(gbase + tok) * 512 + c0] = *(uint4*)r8;
  }
}

// ---------------------------------------------------------------------------
// GEMM: C[M][N](bf16) = A[M][K](bf16) @ BT[N][K](bf16) + bias
// EPI 0: bias   EPI 1: fast-gelu(v+bias)   EPI 2: v+bias+ADD (coalesced)
// 256x256 tile, 8 waves (2Mx4N), 512 threads. 4-slot LDS ring, BK=32/slot.
// Slot s (32KB): A[256][32] at +0, B[256][32] at +8192 (u16). Swizzle:
// in-row 16B slot' = slot ^ ((row>>1)&3), applied on BOTH global source
// column (stage) and ds_read (both-sides-or-neither).
// Pipeline: wait vmcnt(8) -> s_barrier -> STAGE(t+3) -> ds_read(t) -> MFMA.
// ---------------------------------------------------------------------------
template<int EPI>
__global__ __launch_bounds__(512, 2) void gemm256_kernel(
    const u16* __restrict__ A, const u16* __restrict__ BT,
    const float* __restrict__ bias, const u16* __restrict__ ADD,
    u16* __restrict__ Cout, int N, int K)
{
  __shared__ u16 smem[65536];           // 128 KB: 4 ring slots of 16384 u16
  const int nbn = N >> 8;
  int nwg = gridDim.x;
  int bid = blockIdx.x;
  int wgid = (bid & 7) * (nwg >> 3) + (bid >> 3);   // XCD-chunked swizzle (nwg%8==0)
  int bm = wgid / nbn, bn = wgid % nbn;
  size_t m0 = (size_t)bm * 256; int n0 = bn * 256;
  int tid = threadIdx.x;
  int lane = tid & 63, w = tid >> 6;
  int wr = w >> 2, wc = w & 3;          // 2 M-waves x 4 N-waves

  f32x4 zero4 = {0.f, 0.f, 0.f, 0.f};
  f32x4 acc[8][4];
#pragma unroll
  for (int i = 0; i < 8; i++)
#pragma unroll
    for (int j = 0; j < 4; j++) acc[i][j] = zero4;

  // staging geometry: thread t, load j in {0,1} covers row j*128 + (t>>2),
  // 16B slot (t&3). Global col pre-XOR'd: scol = 8*((t&3) ^ ((srow>>1)&3)).
  // ((128+r)>>1)&3 == (r>>1)&3, so scol is identical for both halves.
  int sr = tid >> 2;                    // 0..127
  int scol = (((tid & 3) ^ ((sr >> 1) & 3)) * 8);
  const u16* Abase = A + m0 * (size_t)K;
  const u16* Bbase = BT + (size_t)n0 * K;

  auto STAGE = [&](int slot, int kt){
    u16* s = &smem[slot * 16384];
    gload16(s + w * 512,          Abase + (size_t)sr * K + kt + scol);
    gload16(s + 4096 + w * 512,   Abase + (size_t)(sr + 128) * K + kt + scol);
    gload16(s + 8192 + w * 512,   Bbase + (size_t)sr * K + kt + scol);
    gload16(s + 12288 + w * 512,  Bbase + (size_t)(sr + 128) * K + kt + scol);
  };

  int nk = K >> 5;                      // K-steps of 32 (>= 16 for all our shapes)
  STAGE(0, 0); STAGE(1, 32); STAGE(2, 64);

  int kslot = lane >> 4;
  for (int t = 0; t < nk; ++t){
    // counted wait: allow the stages for t+1, t+2 to remain in flight
    if (t < nk - 2)      asm volatile("s_waitcnt vmcnt(8)" ::: "memory");
    else if (t == nk - 2) asm volatile("s_waitcnt vmcnt(4)" ::: "memory");
    else                  asm volatile("s_waitcnt vmcnt(0)" ::: "memory");
    __builtin_amdgcn_s_barrier();       // raw barrier: no vmcnt drain
    if (t + 3 < nk) STAGE((t + 3) & 3, (t + 3) << 5);   // slot freed at t-1

    const u16* as = &smem[(t & 3) * 16384];
    const u16* bs = as + 8192;
    bf16x8 af[8], bf[4];
#pragma unroll
    for (int m = 0; m < 8; m++){
      int row = wr * 128 + m * 16 + (lane & 15);
      af[m] = *(const bf16x8*)&as[row * 32 + ((kslot ^ ((row >> 1) & 3)) * 8)];
    }
#pragma unroll
    for (int n = 0; n < 4; n++){
      int row = wc * 64 + n * 16 + (lane & 15);
      bf[n] = *(const bf16x8*)&bs[row * 32 + ((kslot ^ ((row >> 1) & 3)) * 8)];
    }
    __builtin_amdgcn_s_setprio(1);
#pragma unroll
    for (int m = 0; m < 8; m++)
#pragma unroll
      for (int n = 0; n < 4; n++)
        acc[m][n] = __builtin_amdgcn_mfma_f32_16x16x32_bf16(af[m], bf[n], acc[m][n], 0, 0, 0);
    __builtin_amdgcn_s_setprio(0);
  }

  __syncthreads();                      // all reads done before C-tile overwrite

  // ---- epilogue phase 1: acc -> LDS C[256][256] (granule XOR by row&31)
#pragma unroll
  for (int n = 0; n < 4; n++){
    int cc = wc * 64 + n * 16 + (lane & 15);
    float bv = bias[n0 + cc];
#pragma unroll
    for (int m = 0; m < 8; m++){
      int r0 = wr * 128 + m * 16 + ((lane >> 4) * 4);
#pragma unroll
      for (int reg = 0; reg < 4; reg++){
        int rr = r0 + reg;
        float v = acc[m][n][reg] + bv;
        if (EPI == 1){
          float h2 = v * v;
          float z = -1.5957691216057308f * (v + 0.044715f * v * h2);
          float e = __expf(z);
          v = v * __builtin_amdgcn_rcpf(1.0f + e);
        }
        smem[rr * 256 + (cc ^ ((rr & 31) << 3))] = f2bf(v);
      }
    }
  }
  __syncthreads();

  // ---- epilogue phase 2: coalesced 16B stores (+ coalesced ADD for EPI2)
#pragma unroll
  for (int i = 0; i < 16; i++){
    int c = i * 512 + tid;
    int row = c >> 5, g = c & 31;
    size_t gro = (m0 + row) * (size_t)N + n0 + g * 8;
    uint4 d = *(const uint4*)&smem[row * 256 + ((g ^ (row & 31)) << 3)];
    if (EPI == 2){
      uint4 av = *(const uint4*)&ADD[gro];
      u16 de[8], ae[8];
      *(uint4*)de = d; *(uint4*)ae = av;
#pragma unroll
      for (int k = 0; k < 8; k++) de[k] = f2bf(bf2f(de[k]) + bf2f(ae[k]));
      d = *(uint4*)de;
    }
    *(uint4*)&Cout[gro] = d;
  }
}

// ---------------------------------------------------------------------------
// K3: attention per (window, head). 1 wave per block. (unchanged)
// ---------------------------------------------------------------------------
__global__ __launch_bounds__(64) void attn_kernel(const u16* __restrict__ QKV,
                                                  u16* __restrict__ O)
{
  __shared__ u16 qs[4096], ks2[4096], vs[4096], ps[4096];
  int blk = blockIdx.x;
  int wg = blk >> 3, h = blk & 7;
  size_t g0 = (size_t)wg * 64;
  int lane = threadIdx.x;
  int lr = lane >> 3, lch = lane & 7;

#pragma unroll
  for (int it = 0; it < 8; it++){
    int r = it * 8 + lr;
    int sc = lch ^ (r & 7);
    {
      uint4 d = *(const uint4*)&QKV[(g0 + r) * 1536 + h * 64 + lch * 8];
      *(uint4*)&qs[r * 64 + sc * 8] = d;
    }
    {
      uint4 d = *(const uint4*)&QKV[(g0 + r) * 1536 + 512 + h * 64 + lch * 8];
      *(uint4*)&ks2[r * 64 + sc * 8] = d;
    }
    {
      uint4 d = *(const uint4*)&QKV[(g0 + r) * 1536 + 1024 + h * 64 + lch * 8];
      u16 e[8]; *(uint4*)e = d;
      int m = r;
#pragma unroll
      for (int j = 0; j < 8; j++){
        int dd = lch * 8 + j;
        int off = dd * 64 + ((((m * 2) ^ ((dd & 7) << 4))) >> 1);
        vs[off] = e[j];
      }
    }
  }
  __syncthreads();

  f32x4 zero4 = {0.f, 0.f, 0.f, 0.f};
  f32x4 s[4][4];
#pragma unroll
  for (int i = 0; i < 4; i++)
#pragma unroll
    for (int j = 0; j < 4; j++) s[i][j] = zero4;

#pragma unroll
  for (int ks = 0; ks < 2; ks++){
    bf16x8 aq[4], bk[4];
#pragma unroll
    for (int mt = 0; mt < 4; mt++){
      int r = mt * 16 + (lane & 15);
      int cb = (ks * 64 + (lane >> 4) * 16) ^ ((r & 7) << 4);
      aq[mt] = *(const bf16x8*)&qs[r * 64 + (cb >> 1)];
    }
#pragma unroll
    for (int nt = 0; nt < 4; nt++){
      int r = nt * 16 + (lane & 15);
      int cb = (ks * 64 + (lane >> 4) * 16) ^ ((r & 7) << 4);
      bk[nt] = *(const bf16x8*)&ks2[r * 64 + (cb >> 1)];
    }
#pragma unroll
    for (int mt = 0; mt < 4; mt++)
#pragma unroll
      for (int nt = 0; nt < 4; nt++)
        s[mt][nt] = __builtin_amdgcn_mfma_f32_16x16x32_bf16(aq[mt], bk[nt], s[mt][nt], 0, 0, 0);
  }

  const float scl = 1.0f / 4096.0f;
#pragma unroll
  for (int mt = 0; mt < 4; mt++){
#pragma unroll
    for (int reg = 0; reg < 4; reg++){
      float mx = -1e30f;
#pragma unroll
      for (int nt = 0; nt < 4; nt++){
        float v = s[mt][nt][reg] * scl; s[mt][nt][reg] = v; mx = fmaxf(mx, v);
      }
#pragma unroll
      for (int d = 1; d < 16; d <<= 1) mx = fmaxf(mx, __shfl_xor(mx, d, 64));
      float sum = 0.f;
#pragma unroll
      for (int nt = 0; nt < 4; nt++){
        float e = __expf(s[mt][nt][reg] - mx); s[mt][nt][reg] = e; sum += e;
      }
#pragma unroll
      for (int d = 1; d < 16; d <<= 1) sum += __shfl_xor(sum, d, 64);
      float inv = 1.0f / sum;
#pragma unroll
      for (int nt = 0; nt < 4; nt++) s[mt][nt][reg] *= inv;
    }
  }

#pragma unroll
  for (int mt = 0; mt < 4; mt++)
#pragma unroll
    for (int reg = 0; reg < 4; reg++){
      int r = mt * 16 + ((lane >> 4) * 4) + reg;
#pragma unroll
      for (int nt = 0; nt < 4; nt++){
        int c = nt * 16 + (lane & 15);
        ps[r * 64 + ((((c * 2) ^ ((r & 7) << 4))) >> 1)] = f2bf(s[mt][nt][reg]);
      }
    }
  __syncthreads();

  f32x4 o[4][4];
#pragma unroll
  for (int i = 0; i < 4; i++)
#pragma unroll
    for (int j = 0; j < 4; j++) o[i][j] = zero4;

#pragma unroll
  for (int ks = 0; ks < 2; ks++){
    bf16x8 ap[4], bv[4];
#pragma unroll
    for (int mt = 0; mt < 4; mt++){
      int r = mt * 16 + (lane & 15);
      int cb = (ks * 64 + (lane >> 4) * 16) ^ ((r & 7) << 4);
      ap[mt] = *(const bf16x8*)&ps[r * 64 + (cb >> 1)];
    }
#pragma unroll
    for (int nt = 0; nt < 4; nt++){
      int dd = nt * 16 + (lane & 15);
      int cb = (ks * 64 + (lane >> 4) * 16) ^ ((dd & 7) << 4);
      bv[nt] = *(const bf16x8*)&vs[dd * 64 + (cb >> 1)];
    }
#pragma unroll
    for (int mt = 0; mt < 4; mt++)
#pragma unroll
      for (int nt = 0; nt < 4; nt++)
        o[mt][nt] = __builtin_amdgcn_mfma_f32_16x16x32_bf16(ap[mt], bv[nt], o[mt][nt], 0, 0, 0);
  }

#pragma unroll
  for (int mt = 0; mt < 4; mt++)
#pragma unroll
    for (int reg = 0; reg < 4; reg++){
      size_t l = mt * 16 + ((lane >> 4) * 4) + reg;
#pragma unroll
      for (int nt = 0; nt < 4; nt++){
        int dd = nt * 16 + (lane & 15);
        O[(g0 + l) * 512 + h * 64 + dd] = f2bf(o[mt][nt][reg]);
      }
    }
}

// ---------------------------------------------------------------------------
// K7: y = x + scatter(MS). (unchanged)
// ---------------------------------------------------------------------------
__global__ __launch_bounds__(256) void scatter_kernel(
    const float* __restrict__ x, const u16* __restrict__ ms, float* __restrict__ y)
{
  __shared__ u16 sm[512 * 64];
  int wg = blockIdx.x;
  int b = wg >> 8, n = wg & 255, wy = n >> 4, wx = n & 15;
  int t = threadIdx.x, lane = t & 63, wv = t >> 6;
  size_t gbase = (size_t)wg * 64;
  int c0 = lane * 8, fs = (2 * lane) & 63;

  for (int it = 0; it < 16; it++){
    int tok = wv * 16 + it;
    uint4 d = *(const uint4*)&ms[(gbase + tok) * 512 + c0];
    u16 e[8]; *(uint4*)e = d;
    int lidx = tok ^ fs;
#pragma unroll
    for (int j = 0; j < 8; j++) sm[(c0 + j) * 64 + lidx] = e[j];
  }
  __syncthreads();

  int l = lane; int yy = l >> 3, xx = l & 7;
  size_t xbase = ((size_t)b * 512) * 16384 + (size_t)(wy * 8 + yy) * 128 + wx * 8 + xx;
#pragma unroll 4
  for (int i = 0; i < 128; i++){
    int c = wv * 128 + i;
    size_t a = xbase + (size_t)c * 16384;
    y[a] = x[a] + bf2f(sm[c * 64 + (l ^ ((2 * (c >> 3)) & 63))]);
  }
}

// ---------------------------------------------------------------------------
extern "C" void kernel_launch(void* const* d_in, const int* in_sizes, int n_in,
                              void* d_out, int out_size, void* d_ws, size_t ws_size,
                              hipStream_t stream)
{
  (void)in_sizes; (void)n_in; (void)out_size; (void)ws_size;
  const float* x      = (const float*)d_in[0];
  const float* gamma1 = (const float*)d_in[1];
  const float* beta1  = (const float*)d_in[2];
  const float* gamma2 = (const float*)d_in[3];
  const float* beta2  = (const float*)d_in[4];
  const float* w_qkv  = (const float*)d_in[5];
  const float* b_qkv  = (const float*)d_in[6];
  const float* w_out  = (const float*)d_in[7];
  const float* b_out  = (const float*)d_in[8];
  const float* w1     = (const float*)d_in[9];
  const float* b1     = (const float*)d_in[10];
  const float* w2     = (const float*)d_in[11];
  const float* b2     = (const float*)d_in[12];
  float* y = (float*)d_out;

  char* ws = (char*)d_ws;
  u16* WqkvT = (u16*)(ws + 0);          // 1536x512  bf16
  u16* WoutT = (u16*)(ws + 1572864);    // 512x512
  u16* W1T   = (u16*)(ws + 2097152);    // 2048x512
  u16* W2T   = (u16*)(ws + 4194304);    // 512x2048
  u16* XN    = (u16*)(ws + 6291456);    // 131072x512 bf16
  u16* O2    = (u16*)(ws + 140509184);  // 131072x512 bf16
  u16* Obuf  = (u16*)(ws + 274726912);  // 131072x512 bf16 (attn out, reused as MS)
  u16* QKV   = (u16*)(ws + 408944640);  // max(QKV 402MB, H 537MB)
  u16* Hbuf  = QKV;
  u16* MS    = Obuf;
  const int M = 131072;

  wt_kernel<<<8 * 24, 256, 0, stream>>>(w_qkv, WqkvT, 512, 1536);
  wt_kernel<<<8 * 8,  256, 0, stream>>>(w_out, WoutT, 512, 512);
  wt_kernel<<<8 * 32, 256, 0, stream>>>(w1, W1T, 512, 2048);
  wt_kernel<<<32 * 8, 256, 0, stream>>>(w2, W2T, 2048, 512);

  ln_kernel<0><<<2048, 256, 0, stream>>>(x, nullptr, gamma1, beta1, XN);
  gemm256_kernel<0><<<(M / 256) * (1536 / 256), 512, 0, stream>>>(XN, WqkvT, b_qkv, nullptr, QKV, 1536, 512);
  attn_kernel<<<16384, 64, 0, stream>>>(QKV, Obuf);
  gemm256_kernel<0><<<(M / 256) * (512 / 256), 512, 0, stream>>>(Obuf, WoutT, b_out, nullptr, O2, 512, 512);
  ln_kernel<1><<<2048, 256, 0, stream>>>(x, O2, gamma2, beta2, XN);
  gemm256_kernel<1><<<(M / 256) * (2048 / 256), 512, 0, stream>>>(XN, W1T, b1, nullptr, Hbuf, 2048, 512);
  gemm256_kernel<2><<<(M / 256) * (512 / 256), 512, 0, stream>>>(Hbuf, W2T, b2, O2, MS, 512, 2048);
  scatter_kernel<<<2048, 256, 0, stream>>>(x, MS, y);
}

// Round 5
// 2348.971 us; speedup vs baseline: 1.2298x; 1.0053x over previous
//
#include <hip/hip_runtime.h>
#include <cstdint>
#include <cstddef>

// ============================================================================
// Swin-style window-attention block, MI355X (gfx950).
// R5: GEMM -> m201-style 8-phase schedule on the proven zero-conflict LDS
// layout. 256x256 tile, BK=64 K-tiles, 2 LDS buffers (128KB), 4 stage units
// per K-tile (A-k0,B-k0,A-k1,B-k1). Per phase: ds_read (4 or 8 b128) ->
// stage 1 unit of next tile -> barrier -> lgkmcnt(0) -> setprio(1) ->
// 16 MFMA -> setprio(0) -> barrier. vmcnt(4) at phases 1 & 3 (never 0
// in-loop). LN / attention / scatter unchanged.
// ============================================================================

typedef unsigned short u16;
typedef unsigned int u32;
typedef __attribute__((ext_vector_type(4))) float f32x4;
typedef __attribute__((ext_vector_type(8))) short bf16x8;

#define DEVINL __device__ __forceinline__

DEVINL float bf2f(u16 u){ union { u32 i; float f; } v; v.i = ((u32)u) << 16; return v.f; }
DEVINL u16 f2bf(float f){
  union { float f; u32 i; } v; v.f = f;
  u32 u = v.i;
  u32 r = (u + 0x7fffu + ((u >> 16) & 1u)) >> 16;   // RNE
  return (u16)r;
}

// async global->LDS, 16B per lane. LDS dest is wave-uniform base (+lane*16 by HW).
DEVINL void gload16(u16* lds, const void* g){
  __builtin_amdgcn_global_load_lds(
      (__attribute__((address_space(1))) u32*)(g),
      (__attribute__((address_space(3))) u32*)(lds), 16, 0, 0);
}

// ---------------------------------------------------------------------------
// K0: weight transpose + cast: in[K][N] fp32 -> out[N][K] bf16
// ---------------------------------------------------------------------------
__global__ __launch_bounds__(256) void wt_kernel(const float* __restrict__ in,
                                                 u16* __restrict__ out, int K, int N)
{
  __shared__ float tile[64][65];
  int tiles_n = N >> 6;
  int tk = blockIdx.x / tiles_n, tn = blockIdx.x % tiles_n;
  int k0 = tk * 64, n0 = tn * 64;
  int lane = threadIdx.x & 63, wr = threadIdx.x >> 6;
#pragma unroll
  for (int i = 0; i < 16; i++){
    int r = wr * 16 + i;
    tile[r][lane] = in[(size_t)(k0 + r) * N + n0 + lane];
  }
  __syncthreads();
#pragma unroll
  for (int i = 0; i < 16; i++){
    int r = wr * 16 + i;
    out[(size_t)(n0 + r) * K + k0 + lane] = f2bf(tile[lane][r]);
  }
}

// ---------------------------------------------------------------------------
// K1 / K4b: window-gather + LayerNorm. (unchanged)
// ---------------------------------------------------------------------------
template<int MODE>
__global__ __launch_bounds__(256) void ln_kernel(
    const float* __restrict__ x, const u16* __restrict__ o2,
    const float* __restrict__ gamma, const float* __restrict__ beta,
    u16* __restrict__ out)
{
  __shared__ u16 sm[512 * 64];
  int wg = blockIdx.x;
  int b = wg >> 8, n = wg & 255, wy = n >> 4, wx = n & 15;
  int t = threadIdx.x, l = t & 63, wv = t >> 6;
  int yy = l >> 3, xx = l & 7;
  size_t xbase = ((size_t)b * 512) * 16384 + (size_t)(wy * 8 + yy) * 128 + wx * 8 + xx;

#pragma unroll 4
  for (int i = 0; i < 128; i++){
    int c = wv * 128 + i;
    float v = x[xbase + (size_t)c * 16384];
    sm[c * 64 + (l ^ ((2 * (c >> 3)) & 63))] = f2bf(v);
  }
  __syncthreads();

  size_t gbase = (size_t)wg * 64;
  int lane = l;
  int c0 = lane * 8;
  int fs = (2 * lane) & 63;
  float g8[8], b8[8];
#pragma unroll
  for (int j = 0; j < 8; j++){ g8[j] = gamma[c0 + j]; b8[j] = beta[c0 + j]; }

  for (int it = 0; it < 16; it++){
    int tok = wv * 16 + it;
    int lidx = tok ^ fs;
    u16 oarr[8];
    if (MODE == 1){
      uint4 ov = *(const uint4*)&o2[(gbase + tok) * 512 + c0];
      *(uint4*)oarr = ov;
    }
    float tv[8]; float sum = 0.f, sq = 0.f;
#pragma unroll
    for (int j = 0; j < 8; j++){
      float v = bf2f(sm[(c0 + j) * 64 + lidx]);
      if (MODE == 1) v += bf2f(oarr[j]);
      tv[j] = v; sum += v; sq += v * v;
    }
#pragma unroll
    for (int d = 1; d < 64; d <<= 1){
      sum += __shfl_xor(sum, d, 64);
      sq  += __shfl_xor(sq, d, 64);
    }
    float mu = sum * (1.0f / 512.0f);
    float var = sq * (1.0f / 512.0f) - mu * mu;
    float rs = rsqrtf(var + 1e-5f);
    u16 r8[8];
#pragma unroll
    for (int j = 0; j < 8; j++) r8[j] = f2bf((tv[j] - mu) * rs * g8[j] + b8[j]);
    *(uint4*)&out[(gbase + tok) * 512 + c0] = *(uint4*)r8;
  }
}

// ---------------------------------------------------------------------------
// GEMM: C[M][N](bf16) = A[M][K](bf16) @ BT[N][K](bf16) + bias
// EPI 0: bias   EPI 1: fast-gelu(v+bias)   EPI 2: v+bias+ADD (coalesced)
// 256x256 tile, 8 waves (2Mx4N), 512 threads. 8-phase pipeline:
// buffer layout (u16, per buffer of 32768): A-k0 @0, A-k1 @8192,
// B-k0 @16384, B-k1 @24576. Each col-block = [256 rows][32 cols],
// 16B slot swizzle slot' = slot ^ ((row>>1)&3) (measured 0 conflicts).
// ---------------------------------------------------------------------------
#define GBAR  __builtin_amdgcn_s_barrier()
#define LGKM0 do { asm volatile("s_waitcnt lgkmcnt(0)" ::: "memory"); \
                   __builtin_amdgcn_sched_barrier(0); } while(0)
#define VM4   asm volatile("s_waitcnt vmcnt(4)" ::: "memory")
#define VM0   asm volatile("s_waitcnt vmcnt(0)" ::: "memory")

DEVINL void mfma_blk(f32x4 (&acc)[8][4], const bf16x8 (&ar)[4], const bf16x8 (&br)[4], int mh){
  __builtin_amdgcn_s_setprio(1);
#pragma unroll
  for (int m = 0; m < 4; m++)
#pragma unroll
    for (int n = 0; n < 4; n++)
      acc[mh * 4 + m][n] = __builtin_amdgcn_mfma_f32_16x16x32_bf16(ar[m], br[n], acc[mh * 4 + m][n], 0, 0, 0);
  __builtin_amdgcn_s_setprio(0);
}

template<int EPI>
__global__ __launch_bounds__(512, 2) void gemm256_kernel(
    const u16* __restrict__ A, const u16* __restrict__ BT,
    const float* __restrict__ bias, const u16* __restrict__ ADD,
    u16* __restrict__ Cout, int N, int K)
{
  __shared__ u16 smem[65536];           // 128 KB: 2 buffers of 32768 u16
  const int nbn = N >> 8;
  int nwg = gridDim.x;
  int bid = blockIdx.x;
  int wgid = (bid & 7) * (nwg >> 3) + (bid >> 3);   // XCD-chunked swizzle (nwg%8==0)
  int bm = wgid / nbn, bn = wgid % nbn;
  size_t m0 = (size_t)bm * 256; int n0 = bn * 256;
  int tid = threadIdx.x;
  int lane = tid & 63, w = tid >> 6;
  int wr = w >> 2, wc = w & 3;          // 2 M-waves x 4 N-waves
  int kslot = lane >> 4;

  f32x4 zero4 = {0.f, 0.f, 0.f, 0.f};
  f32x4 acc[8][4];
#pragma unroll
  for (int i = 0; i < 8; i++)
#pragma unroll
    for (int j = 0; j < 4; j++) acc[i][j] = zero4;

  // staging: per unit (16KB = [256 rows][32 cols]), each wave issues 2 gloads.
  // Linear LDS dest; global source column pre-XOR'd (both-sides swizzle).
  int sr = tid >> 2;                    // 0..127
  int scol = (((tid & 3) ^ ((sr >> 1) & 3)) * 8);
  const u16* Abase = A + m0 * (size_t)K;
  const u16* Bbase = BT + (size_t)n0 * K;

  auto SU = [&](int b16, const u16* src, int kcol){
    gload16(&smem[b16] + w * 512,        src + (size_t)sr * K + kcol);
    gload16(&smem[b16] + 4096 + w * 512, src + (size_t)(sr + 128) * K + kcol);
  };

  auto RDA = [&](bf16x8 (&ar)[4], int cb, int mh, int ks){
#pragma unroll
    for (int m = 0; m < 4; m++){
      int row = wr * 128 + (mh * 4 + m) * 16 + (lane & 15);
      ar[m] = *(const bf16x8*)&smem[cb + ks * 8192 + row * 32 + ((kslot ^ ((row >> 1) & 3)) * 8)];
    }
  };
  auto RDB = [&](bf16x8 (&br)[4], int cb, int ks){
#pragma unroll
    for (int n = 0; n < 4; n++){
      int row = wc * 64 + n * 16 + (lane & 15);
      br[n] = *(const bf16x8*)&smem[cb + 16384 + ks * 8192 + row * 32 + ((kslot ^ ((row >> 1) & 3)) * 8)];
    }
  };

  // prologue: 4 units of K-tile 0 into buffer 0; guarantee units 0,1 landed.
  SU(0,     Abase, scol);        // u0: A-k0
  SU(16384, Bbase, scol);        // u1: B-k0
  SU(8192,  Abase, 32 + scol);   // u2: A-k1
  SU(24576, Bbase, 32 + scol);   // u3: B-k1
  VM4;
  GBAR;

  int nk = K >> 6;
  for (int t = 0; t < nk; ++t){
    int cb = (t & 1) << 15;
    int nb = ((t + 1) & 1) << 15;
    int ktn = (t + 1) << 6;
    bool st = (t + 1 < nk);
    bf16x8 areg[4], breg[4];

    // ---- phase 0: B-k0 + A[m-lo]-k0 ; stage A-k0(next)
    RDB(breg, cb, 0);
    RDA(areg, cb, 0, 0);
    if (st) SU(nb, Abase, ktn + scol);
    GBAR; LGKM0;
    mfma_blk(acc, areg, breg, 0);
    GBAR;
    // ---- phase 1: A[m-hi]-k0 ; stage B-k0(next) ; vmcnt -> units 2,3 of t
    RDA(areg, cb, 1, 0);
    if (st){ SU(nb + 16384, Bbase, ktn + scol); VM4; } else { VM0; }
    GBAR; LGKM0;
    mfma_blk(acc, areg, breg, 1);
    GBAR;
    // ---- phase 2: B-k1 + A[m-lo]-k1 ; stage A-k1(next)
    RDB(breg, cb, 1);
    RDA(areg, cb, 0, 1);
    if (st) SU(nb + 8192, Abase, ktn + 32 + scol);
    GBAR; LGKM0;
    mfma_blk(acc, areg, breg, 0);
    GBAR;
    // ---- phase 3: A[m-hi]-k1 ; stage B-k1(next) ; vmcnt -> units 0,1 of t+1
    RDA(areg, cb, 1, 1);
    if (st){ SU(nb + 24576, Bbase, ktn + 32 + scol); VM4; }
    GBAR; LGKM0;
    mfma_blk(acc, areg, breg, 1);
    GBAR;
  }

  // ---- epilogue phase 1: acc -> LDS C[256][256] (granule XOR by row&31)
#pragma unroll
  for (int n = 0; n < 4; n++){
    int cc = wc * 64 + n * 16 + (lane & 15);
    float bv = bias[n0 + cc];
#pragma unroll
    for (int m = 0; m < 8; m++){
      int r0 = wr * 128 + m * 16 + ((lane >> 4) * 4);
#pragma unroll
      for (int reg = 0; reg < 4; reg++){
        int rr = r0 + reg;
        float v = acc[m][n][reg] + bv;
        if (EPI == 1){
          float h2 = v * v;
          float z = -1.5957691216057308f * (v + 0.044715f * v * h2);
          float e = __expf(z);
          v = v * __builtin_amdgcn_rcpf(1.0f + e);
        }
        smem[rr * 256 + (cc ^ ((rr & 31) << 3))] = f2bf(v);
      }
    }
  }
  __syncthreads();

  // ---- epilogue phase 2: coalesced 16B stores (+ coalesced ADD for EPI2)
#pragma unroll
  for (int i = 0; i < 16; i++){
    int c = i * 512 + tid;
    int row = c >> 5, g = c & 31;
    size_t gro = (m0 + row) * (size_t)N + n0 + g * 8;
    uint4 d = *(const uint4*)&smem[row * 256 + ((g ^ (row & 31)) << 3)];
    if (EPI == 2){
      uint4 av = *(const uint4*)&ADD[gro];
      u16 de[8], ae[8];
      *(uint4*)de = d; *(uint4*)ae = av;
#pragma unroll
      for (int k = 0; k < 8; k++) de[k] = f2bf(bf2f(de[k]) + bf2f(ae[k]));
      d = *(uint4*)de;
    }
    *(uint4*)&Cout[gro] = d;
  }
}

// ---------------------------------------------------------------------------
// K3: attention per (window, head). 1 wave per block. (unchanged)
// ---------------------------------------------------------------------------
__global__ __launch_bounds__(64) void attn_kernel(const u16* __restrict__ QKV,
                                                  u16* __restrict__ O)
{
  __shared__ u16 qs[4096], ks2[4096], vs[4096], ps[4096];
  int blk = blockIdx.x;
  int wg = blk >> 3, h = blk & 7;
  size_t g0 = (size_t)wg * 64;
  int lane = threadIdx.x;
  int lr = lane >> 3, lch = lane & 7;

#pragma unroll
  for (int it = 0; it < 8; it++){
    int r = it * 8 + lr;
    int sc = lch ^ (r & 7);
    {
      uint4 d = *(const uint4*)&QKV[(g0 + r) * 1536 + h * 64 + lch * 8];
      *(uint4*)&qs[r * 64 + sc * 8] = d;
    }
    {
      uint4 d = *(const uint4*)&QKV[(g0 + r) * 1536 + 512 + h * 64 + lch * 8];
      *(uint4*)&ks2[r * 64 + sc * 8] = d;
    }
    {
      uint4 d = *(const uint4*)&QKV[(g0 + r) * 1536 + 1024 + h * 64 + lch * 8];
      u16 e[8]; *(uint4*)e = d;
      int m = r;
#pragma unroll
      for (int j = 0; j < 8; j++){
        int dd = lch * 8 + j;
        int off = dd * 64 + ((((m * 2) ^ ((dd & 7) << 4))) >> 1);
        vs[off] = e[j];
      }
    }
  }
  __syncthreads();

  f32x4 zero4 = {0.f, 0.f, 0.f, 0.f};
  f32x4 s[4][4];
#pragma unroll
  for (int i = 0; i < 4; i++)
#pragma unroll
    for (int j = 0; j < 4; j++) s[i][j] = zero4;

#pragma unroll
  for (int ks = 0; ks < 2; ks++){
    bf16x8 aq[4], bk[4];
#pragma unroll
    for (int mt = 0; mt < 4; mt++){
      int r = mt * 16 + (lane & 15);
      int cb = (ks * 64 + (lane >> 4) * 16) ^ ((r & 7) << 4);
      aq[mt] = *(const bf16x8*)&qs[r * 64 + (cb >> 1)];
    }
#pragma unroll
    for (int nt = 0; nt < 4; nt++){
      int r = nt * 16 + (lane & 15);
      int cb = (ks * 64 + (lane >> 4) * 16) ^ ((r & 7) << 4);
      bk[nt] = *(const bf16x8*)&ks2[r * 64 + (cb >> 1)];
    }
#pragma unroll
    for (int mt = 0; mt < 4; mt++)
#pragma unroll
      for (int nt = 0; nt < 4; nt++)
        s[mt][nt] = __builtin_amdgcn_mfma_f32_16x16x32_bf16(aq[mt], bk[nt], s[mt][nt], 0, 0, 0);
  }

  const float scl = 1.0f / 4096.0f;
#pragma unroll
  for (int mt = 0; mt < 4; mt++){
#pragma unroll
    for (int reg = 0; reg < 4; reg++){
      float mx = -1e30f;
#pragma unroll
      for (int nt = 0; nt < 4; nt++){
        float v = s[mt][nt][reg] * scl; s[mt][nt][reg] = v; mx = fmaxf(mx, v);
      }
#pragma unroll
      for (int d = 1; d < 16; d <<= 1) mx = fmaxf(mx, __shfl_xor(mx, d, 64));
      float sum = 0.f;
#pragma unroll
      for (int nt = 0; nt < 4; nt++){
        float e = __expf(s[mt][nt][reg] - mx); s[mt][nt][reg] = e; sum += e;
      }
#pragma unroll
      for (int d = 1; d < 16; d <<= 1) sum += __shfl_xor(sum, d, 64);
      float inv = 1.0f / sum;
#pragma unroll
      for (int nt = 0; nt < 4; nt++) s[mt][nt][reg] *= inv;
    }
  }

#pragma unroll
  for (int mt = 0; mt < 4; mt++)
#pragma unroll
    for (int reg = 0; reg < 4; reg++){
      int r = mt * 16 + ((lane >> 4) * 4) + reg;
#pragma unroll
      for (int nt = 0; nt < 4; nt++){
        int c = nt * 16 + (lane & 15);
        ps[r * 64 + ((((c * 2) ^ ((r & 7) << 4))) >> 1)] = f2bf(s[mt][nt][reg]);
      }
    }
  __syncthreads();

  f32x4 o[4][4];
#pragma unroll
  for (int i = 0; i < 4; i++)
#pragma unroll
    for (int j = 0; j < 4; j++) o[i][j] = zero4;

#pragma unroll
  for (int ks = 0; ks < 2; ks++){
    bf16x8 ap[4], bv[4];
#pragma unroll
    for (int mt = 0; mt < 4; mt++){
      int r = mt * 16 + (lane & 15);
      int cb = (ks * 64 + (lane >> 4) * 16) ^ ((r & 7) << 4);
      ap[mt] = *(const bf16x8*)&ps[r * 64 + (cb >> 1)];
    }
#pragma unroll
    for (int nt = 0; nt < 4; nt++){
      int dd = nt * 16 + (lane & 15);
      int cb = (ks * 64 + (lane >> 4) * 16) ^ ((dd & 7) << 4);
      bv[nt] = *(const bf16x8*)&vs[dd * 64 + (cb >> 1)];
    }
#pragma unroll
    for (int mt = 0; mt < 4; mt++)
#pragma unroll
      for (int nt = 0; nt < 4; nt++)
        o[mt][nt] = __builtin_amdgcn_mfma_f32_16x16x32_bf16(ap[mt], bv[nt], o[mt][nt], 0, 0, 0);
  }

#pragma unroll
  for (int mt = 0; mt < 4; mt++)
#pragma unroll
    for (int reg = 0; reg < 4; reg++){
      size_t l = mt * 16 + ((lane >> 4) * 4) + reg;
#pragma unroll
      for (int nt = 0; nt < 4; nt++){
        int dd = nt * 16 + (lane & 15);
        O[(g0 + l) * 512 + h * 64 + dd] = f2bf(o[mt][nt][reg]);
      }
    }
}

// ---------------------------------------------------------------------------
// K7: y = x + scatter(MS). (unchanged)
// ---------------------------------------------------------------------------
__global__ __launch_bounds__(256) void scatter_kernel(
    const float* __restrict__ x, const u16* __restrict__ ms, float* __restrict__ y)
{
  __shared__ u16 sm[512 * 64];
  int wg = blockIdx.x;
  int b = wg >> 8, n = wg & 255, wy = n >> 4, wx = n & 15;
  int t = threadIdx.x, lane = t & 63, wv = t >> 6;
  size_t gbase = (size_t)wg * 64;
  int c0 = lane * 8, fs = (2 * lane) & 63;

  for (int it = 0; it < 16; it++){
    int tok = wv * 16 + it;
    uint4 d = *(const uint4*)&ms[(gbase + tok) * 512 + c0];
    u16 e[8]; *(uint4*)e = d;
    int lidx = tok ^ fs;
#pragma unroll
    for (int j = 0; j < 8; j++) sm[(c0 + j) * 64 + lidx] = e[j];
  }
  __syncthreads();

  int l = lane; int yy = l >> 3, xx = l & 7;
  size_t xbase = ((size_t)b * 512) * 16384 + (size_t)(wy * 8 + yy) * 128 + wx * 8 + xx;
#pragma unroll 4
  for (int i = 0; i < 128; i++){
    int c = wv * 128 + i;
    size_t a = xbase + (size_t)c * 16384;
    y[a] = x[a] + bf2f(sm[c * 64 + (l ^ ((2 * (c >> 3)) & 63))]);
  }
}

// ---------------------------------------------------------------------------
extern "C" void kernel_launch(void* const* d_in, const int* in_sizes, int n_in,
                              void* d_out, int out_size, void* d_ws, size_t ws_size,
                              hipStream_t stream)
{
  (void)in_sizes; (void)n_in; (void)out_size; (void)ws_size;
  const float* x      = (const float*)d_in[0];
  const float* gamma1 = (const float*)d_in[1];
  const float* beta1  = (const float*)d_in[2];
  const float* gamma2 = (const float*)d_in[3];
  const float* beta2  = (const float*)d_in[4];
  const float* w_qkv  = (const float*)d_in[5];
  const float* b_qkv  = (const float*)d_in[6];
  const float* w_out  = (const float*)d_in[7];
  const float* b_out  = (const float*)d_in[8];
  const float* w1     = (const float*)d_in[9];
  const float* b1     = (const float*)d_in[10];
  const float* w2     = (const float*)d_in[11];
  const float* b2     = (const float*)d_in[12];
  float* y = (float*)d_out;

  char* ws = (char*)d_ws;
  u16* WqkvT = (u16*)(ws + 0);          // 1536x512  bf16
  u16* WoutT = (u16*)(ws + 1572864);    // 512x512
  u16* W1T   = (u16*)(ws + 2097152);    // 2048x512
  u16* W2T   = (u16*)(ws + 4194304);    // 512x2048
  u16* XN    = (u16*)(ws + 6291456);    // 131072x512 bf16
  u16* O2    = (u16*)(ws + 140509184);  // 131072x512 bf16
  u16* Obuf  = (u16*)(ws + 274726912);  // 131072x512 bf16 (attn out, reused as MS)
  u16* QKV   = (u16*)(ws + 408944640);  // max(QKV 402MB, H 537MB)
  u16* Hbuf  = QKV;
  u16* MS    = Obuf;
  const int M = 131072;

  wt_kernel<<<8 * 24, 256, 0, stream>>>(w_qkv, WqkvT, 512, 1536);
  wt_kernel<<<8 * 8,  256, 0, stream>>>(w_out, WoutT, 512, 512);
  wt_kernel<<<8 * 32, 256, 0, stream>>>(w1, W1T, 512, 2048);
  wt_kernel<<<32 * 8, 256, 0, stream>>>(w2, W2T, 2048, 512);

  ln_kernel<0><<<2048, 256, 0, stream>>>(x, nullptr, gamma1, beta1, XN);
  gemm256_kernel<0><<<(M / 256) * (1536 / 256), 512, 0, stream>>>(XN, WqkvT, b_qkv, nullptr, QKV, 1536, 512);
  attn_kernel<<<16384, 64, 0, stream>>>(QKV, Obuf);
  gemm256_kernel<0><<<(M / 256) * (512 / 256), 512, 0, stream>>>(Obuf, WoutT, b_out, nullptr, O2, 512, 512);
  ln_kernel<1><<<2048, 256, 0, stream>>>(x, O2, gamma2, beta2, XN);
  gemm256_kernel<1><<<(M / 256) * (2048 / 256), 512, 0, stream>>>(XN, W1T, b1, nullptr, Hbuf, 2048, 512);
  gemm256_kernel<2><<<(M / 256) * (512 / 256), 512, 0, stream>>>(Hbuf, W2T, b2, O2, MS, 512, 2048);
  scatter_kernel<<<2048, 256, 0, stream>>>(x, MS, y);
}